// Round 4
// baseline (317.708 us; speedup 1.0000x reference)
//
#include <hip/hip_runtime.h>
#include <hip/hip_fp16.h>

#define IH   96
#define IW   320
#define NB   4
#define CIN  128
#define COUT 128
#define NKP  9
#define HW   (IH*IW)

typedef float    f32x4 __attribute__((ext_vector_type(4)));
typedef _Float16 f16x8 __attribute__((ext_vector_type(8)));

__device__ __forceinline__ unsigned splat_lo(unsigned u) { return (u & 0xffffu) | (u << 16); }
__device__ __forceinline__ unsigned splat_hi(unsigned u) { return (u >> 16) | (u & 0xffff0000u); }

// ================= pre-pass: transpose + weight prepack =================
// blocks [0,3840): NCHW f32 -> NHWC f16    [3840,4416): weight -> [kp][Cout][Cin] f16
__global__ __launch_bounds__(256) void k_pre(const float* __restrict__ feat,
                                             const float* __restrict__ w,
                                             unsigned* __restrict__ nhwc,
                                             _Float16* __restrict__ wb) {
    __shared__ float tile[32][129];
    int bid = blockIdx.x;
    int tid = threadIdx.x;

    if (bid < 3840) {                     // ---- transpose: b*IH*10 + y*10 + xc ----
        int xc = bid % 10;
        int by = bid / 10;
        int y = by % IH;
        int b = by / IH;
        int x0 = xc * 32;
        const float* src = feat + (size_t)b * CIN * HW + (size_t)y * IW + x0;
#pragma unroll
        for (int i = 0; i < 16; ++i) {
            int idx = tid + 256 * i;
            int c = idx >> 5, xl = idx & 31;
            tile[xl][c] = src[(size_t)c * HW + xl];
        }
        __syncthreads();
        unsigned* d = nhwc + ((size_t)(b * IH + y) * IW + x0) * 64;
#pragma unroll
        for (int i = 0; i < 8; ++i) {
            int idx = tid + 256 * i;
            int c2 = idx & 63, xl = idx >> 6;
            __half2 p;
            p.x = __float2half(tile[xl][2 * c2]);
            p.y = __float2half(tile[xl][2 * c2 + 1]);
            d[xl * 64 + c2] = *(unsigned*)&p;
        }
        return;
    }
    bid -= 3840;                          // ---- weight prepack ----
    int idx = bid * 256 + tid;            // 9*128*128 = 147456 exact
    int kp = idx >> 14;
    int cout = (idx >> 7) & 127;
    int c = idx & 127;
    wb[idx] = (_Float16)w[(cout * CIN + c) * NKP + kp];
}

// ================= main fused kernel =================
// 64 positions/block (one row strip), 4 waves. Meta computed IN-KERNEL (lanes 0-15
// per wave) into double-buffered LDS metabuf; sampling reads it via uniform
// ds_read_b128 broadcast (no scalar-path streaming, no meta HBM traffic).
__global__ __launch_bounds__(256, 6) void k_main(const float* __restrict__ off,
                                                 const char* __restrict__ fb,
                                                 const _Float16* __restrict__ wb,
                                                 float* __restrict__ out) {
    __shared__ unsigned colbuf[64 * 64];      // 16 KB, XOR-swizzled
    __shared__ uint4 metabuf[2][64];          // 2 KB

    const int tid  = threadIdx.x;
    const int lane = tid & 63;
    const int wv   = tid >> 6;
    const int posl = lane & 15;
    const int hi   = lane >> 4;
    const int l4   = lane << 2;

    int bid = (blockIdx.x & 7) * 240 + (blockIdx.x >> 3);   // XCD chunked swizzle (1920=8*240)
    const int n0  = bid * 64;
    const int b   = n0 / HW;
    const int rem = n0 - b * HW;
    const int ho  = rem / IW;
    const int wo0 = rem - ho * IW;

    const bool mlane = (lane < 16);
    const int mp = wv * 16 + posl;            // item this lane meta-computes
    const int rowoff = ho * IW + wo0 + mp;

    // --- in-kernel meta for kernel-tap k -> metabuf[k&1][mp] (16 B/item) ---
    auto metacalc = [&](int k) {
        if (!mlane) return;
        const float* basep = off + (size_t)(b * 18 + 2 * k) * HW + rowoff;
        float dy = basep[0];
        float dx = basep[HW];
        int ky = k / 3, kx = k - 3 * (k / 3);
        float py = (float)(ho - 1 + ky) + dy;
        float px = (float)(wo0 + mp - 1 + kx) + dx;
        float y0f = floorf(py), x0f = floorf(px);
        float wy1 = py - y0f, wx1 = px - x0f;
        float wy0 = 1.f - wy1, wx0 = 1.f - wx1;
        int y0 = (int)y0f, x0 = (int)x0f, y1 = y0 + 1, x1 = x0 + 1;
        wy0 = (y0 >= 0 && y0 < IH) ? wy0 : 0.f;
        wy1 = (y1 >= 0 && y1 < IH) ? wy1 : 0.f;
        wx0 = (x0 >= 0 && x0 < IW) ? wx0 : 0.f;
        wx1 = (x1 >= 0 && x1 < IW) ? wx1 : 0.f;
        int yc0 = min(max(y0, 0), IH - 1), yc1 = min(max(y1, 0), IH - 1);
        int xc0 = min(max(x0, 0), IW - 1), xc1 = min(max(x1, 0), IW - 1);
        uint4 m;
        m.x = ((unsigned)((b * IH + yc0) * IW + xc0) << 8) | (unsigned)(xc1 - xc0);
        m.y = (unsigned)((b * IH + yc1) * IW + xc0) << 8;
        __half2 wz; wz.x = __float2half(wy0 * wx0); wz.y = __float2half(wy0 * wx1);
        __half2 ww; ww.x = __float2half(wy1 * wx0); ww.y = __float2half(wy1 * wx1);
        m.z = *(unsigned*)&wz;
        m.w = *(unsigned*)&ww;
        metabuf[k & 1][mp] = m;
    };

    f32x4 acc[2][4];
#pragma unroll
    for (int mi = 0; mi < 2; ++mi)
#pragma unroll
        for (int nj = 0; nj < 4; ++nj)
            acc[mi][nj] = (f32x4){0.f, 0.f, 0.f, 0.f};

    metacalc(0);
    __syncthreads();

    for (int kp = 0; kp < NKP; ++kp) {
        const int cur = kp & 1;
        // ---- sample phase: wave fills positions [16*wv, 16*wv+16) ----
#pragma unroll
        for (int i = 0; i < 16; ++i) {
            int p = (wv << 4) + i;
            uint4 m = metabuf[cur][p];        // uniform ds_read_b128 -> broadcast
            unsigned d  = (m.x & 1u) << 8;
            unsigned a00 = m.x & 0xffffff00u;
            unsigned u00 = *(const unsigned*)(fb + a00 + l4);
            unsigned u01 = *(const unsigned*)(fb + (a00 + d) + l4);
            unsigned u10 = *(const unsigned*)(fb + m.y + l4);
            unsigned u11 = *(const unsigned*)(fb + (m.y + d) + l4);
            unsigned w00 = splat_lo(m.z), w01 = splat_hi(m.z);
            unsigned w10 = splat_lo(m.w), w11 = splat_hi(m.w);
            __half2 s = __hmul2(*(__half2*)&w00, *(__half2*)&u00);
            s = __hfma2(*(__half2*)&w01, *(__half2*)&u01, s);
            s = __hfma2(*(__half2*)&w10, *(__half2*)&u10, s);
            s = __hfma2(*(__half2*)&w11, *(__half2*)&u11, s);
            colbuf[(p << 6) + (lane ^ ((p & 7) << 2))] = *(unsigned*)&s;
        }
        if (kp < NKP - 1) metacalc(kp + 1);   // meta for next tap, other buffer
        __syncthreads();

        // ---- MFMA phase: wave tile = 32 Cout rows x 64 positions ----
        const _Float16* wkbase =
            wb + (size_t)kp * COUT * CIN + (size_t)(wv * 32 + posl) * CIN + 8 * hi;
#pragma unroll
        for (int c0 = 0; c0 < CIN; c0 += 32) {
            f16x8 a0 = *(const f16x8*)(wkbase + c0);
            f16x8 a1 = *(const f16x8*)(wkbase + 16 * CIN + c0);
            int cb = (c0 >> 1) + 4 * hi;
#pragma unroll
            for (int nj = 0; nj < 4; ++nj) {
                int pos = nj * 16 + posl;
                f16x8 bfr = *(const f16x8*)(&colbuf[(pos << 6) + (cb ^ ((pos & 7) << 2))]);
                acc[0][nj] = __builtin_amdgcn_mfma_f32_16x16x32_f16(a0, bfr, acc[0][nj], 0, 0, 0);
                acc[1][nj] = __builtin_amdgcn_mfma_f32_16x16x32_f16(a1, bfr, acc[1][nj], 0, 0, 0);
            }
        }
        __syncthreads();
    }

    // ---- epilogue: C/D layout col=lane&15, row=hi*4+r ----
#pragma unroll
    for (int mi = 0; mi < 2; ++mi) {
#pragma unroll
        for (int nj = 0; nj < 4; ++nj) {
            int cout = wv * 32 + mi * 16 + 4 * hi;
            int wo = wo0 + nj * 16 + posl;
            float* op = out + ((size_t)(b * COUT + cout) * IH + ho) * IW + wo;
#pragma unroll
            for (int r = 0; r < 4; ++r)
                op[(size_t)r * HW] = acc[mi][nj][r];
        }
    }
}

extern "C" void kernel_launch(void* const* d_in, const int* in_sizes, int n_in,
                              void* d_out, int out_size, void* d_ws, size_t ws_size,
                              hipStream_t stream) {
    const float* features = (const float*)d_in[0];
    const float* offsets  = (const float*)d_in[1];
    const float* weight   = (const float*)d_in[2];
    float* out = (float*)d_out;

    unsigned*  nhwc = (unsigned*)d_ws;                                     // 31,457,280 B
    _Float16*  wbuf = (_Float16*)((char*)d_ws + (size_t)NB * HW * CIN * 2);

    hipLaunchKernelGGL(k_pre, dim3(4416), dim3(256), 0, stream,
                       features, weight, nhwc, wbuf);
    hipLaunchKernelGGL(k_main, dim3((NB * HW) / 64), dim3(256), 0, stream,
                       offsets, (const char*)nhwc, wbuf, out);
}

// Round 5
// 273.823 us; speedup vs baseline: 1.1603x; 1.1603x over previous
//
#include <hip/hip_runtime.h>
#include <hip/hip_fp16.h>

#define IH   96
#define IW   320
#define NB   4
#define CIN  128
#define COUT 128
#define NKP  9
#define HW   (IH*IW)

typedef float    f32x4 __attribute__((ext_vector_type(4)));
typedef _Float16 f16x8 __attribute__((ext_vector_type(8)));
typedef unsigned u32x4 __attribute__((ext_vector_type(4)));

// ================= pre-pass: transpose + swizzled weight prepack =================
// blocks [0,3840): NCHW f32 -> NHWC f16    [3840,4416): weight -> [kp][row][c^((row&7)<<3)]
__global__ __launch_bounds__(256) void k_pre(const float* __restrict__ feat,
                                             const float* __restrict__ w,
                                             unsigned* __restrict__ nhwc,
                                             _Float16* __restrict__ wb) {
    __shared__ float tile[32][129];
    int bid = blockIdx.x;
    int tid = threadIdx.x;

    if (bid < 3840) {                     // ---- transpose: b*IH*10 + y*10 + xc ----
        int xc = bid % 10;
        int by = bid / 10;
        int y = by % IH;
        int b = by / IH;
        int x0 = xc * 32;
        const float* src = feat + (size_t)b * CIN * HW + (size_t)y * IW + x0;
#pragma unroll
        for (int i = 0; i < 16; ++i) {
            int idx = tid + 256 * i;
            int c = idx >> 5, xl = idx & 31;
            tile[xl][c] = src[(size_t)c * HW + xl];
        }
        __syncthreads();
        unsigned* d = nhwc + ((size_t)(b * IH + y) * IW + x0) * 64;
#pragma unroll
        for (int i = 0; i < 8; ++i) {
            int idx = tid + 256 * i;
            int c2 = idx & 63, xl = idx >> 6;
            __half2 p;
            p.x = __float2half(tile[xl][2 * c2]);
            p.y = __float2half(tile[xl][2 * c2 + 1]);
            d[xl * 64 + c2] = *(unsigned*)&p;
        }
        return;
    }
    bid -= 3840;                          // ---- weight prepack (pre-swizzled for LDS) ----
    int d = bid * 256 + tid;              // dest: kp*16384 + row*128 + j
    int kp = d >> 14;
    int row = (d >> 7) & 127;
    int j = d & 127;
    int csrc = j ^ ((row & 7) << 3);      // XOR swizzle (bank-spread for ds_read_b128)
    wb[d] = (_Float16)w[(row * CIN + csrc) * NKP + kp];
}

// ================= main kernel =================
// Wave tile: 16 positions x 128 Cout. B-fragments built in registers directly from
// dwordx4 gathers (lane (p=lane&15, kg=lane>>4) gathers channels 8kg..8kg+7).
// Weights double-buffered in LDS (2x32KB), staged reg->LDS from pre-swizzled wbuf.
// One barrier per tap; no sampling barriers; waves otherwise independent.
__global__ __launch_bounds__(256, 2) void k_main(const float* __restrict__ off,
                                                 const char* __restrict__ fb,
                                                 const _Float16* __restrict__ wbuf,
                                                 float* __restrict__ out) {
    __shared__ _Float16 wlds[2][16384];   // 2 x 32 KB

    const int tid  = threadIdx.x;
    const int lane = tid & 63;
    const int wv   = tid >> 6;
    const int posl = lane & 15;
    const int kg   = lane >> 4;

    const int bid = (blockIdx.x & 7) * 240 + (blockIdx.x >> 3);  // XCD swizzle, 1920=8*240
    const int n0  = bid * 64;
    const int b   = n0 / HW;
    const int rem = n0 - b * HW;
    const int ho  = rem / IW;
    const int wox = rem - ho * IW + wv * 16 + posl;   // this lane's output x

    const float* offp = off + (size_t)b * 18 * HW + ho * IW + wox;
    const unsigned bkg = ((unsigned)(b * HW) << 8) + 16 * kg;   // batch base + k-group byte off

    // A-frag LDS byte offsets per cslice s (within one 32KB tap buffer)
    const int xorv = (posl & 7) << 4;
    int aoff[4];
#pragma unroll
    for (int s = 0; s < 4; ++s)
        aoff[s] = posl * 256 + ((64 * s + 16 * kg) ^ xorv);

    const int stg = wv * 4096 + lane * 8;             // staging f16 index (linear)

    f32x4 acc[8];
#pragma unroll
    for (int m = 0; m < 8; ++m) acc[m] = (f32x4){0.f, 0.f, 0.f, 0.f};

    // ---- prologue: stage tap 0 into buffer 0 ----
    {
        const _Float16* src = wbuf + stg;
#pragma unroll
        for (int j = 0; j < 8; ++j) {
            f16x8 v = *(const f16x8*)(src + j * 512);
            *(f16x8*)(&wlds[0][stg + j * 512]) = v;
        }
    }
    __syncthreads();

    for (int kp = 0; kp < NKP; ++kp) {
        const char* wc = (const char*)&wlds[kp & 1][0];
        const bool more = (kp + 1 < NKP);

        // ---- issue next tap's weight staging loads EARLY (write to LDS late) ----
        f16x8 stgv[8];
        if (more) {
            const _Float16* src = wbuf + (kp + 1) * 16384 + stg;
#pragma unroll
            for (int j = 0; j < 8; ++j)
                stgv[j] = *(const f16x8*)(src + j * 512);
        }

        // ---- meta (per-lane, its own position) ----
        const int ky = kp / 3, kx = kp - 3 * (kp / 3);
        float dy = offp[(size_t)(2 * kp) * HW];
        float dx = offp[(size_t)(2 * kp + 1) * HW];
        float py = (float)(ho - 1 + ky) + dy;
        float px = (float)(wox - 1 + kx) + dx;
        float y0f = floorf(py), x0f = floorf(px);
        float wy1 = py - y0f, wx1 = px - x0f;
        float wy0 = 1.f - wy1, wx0 = 1.f - wx1;
        int y0 = (int)y0f, x0 = (int)x0f, y1 = y0 + 1, x1 = x0 + 1;
        wy0 = (y0 >= 0 && y0 < IH) ? wy0 : 0.f;
        wy1 = (y1 >= 0 && y1 < IH) ? wy1 : 0.f;
        wx0 = (x0 >= 0 && x0 < IW) ? wx0 : 0.f;
        wx1 = (x1 >= 0 && x1 < IW) ? wx1 : 0.f;
        int yr0 = min(max(y0, 0), IH - 1) * IW, yr1 = min(max(y1, 0), IH - 1) * IW;
        int xc0 = min(max(x0, 0), IW - 1), xc1 = min(max(x1, 0), IW - 1);
        unsigned a00 = bkg + ((unsigned)(yr0 + xc0) << 8);
        unsigned a01 = bkg + ((unsigned)(yr0 + xc1) << 8);
        unsigned a10 = bkg + ((unsigned)(yr1 + xc0) << 8);
        unsigned a11 = bkg + ((unsigned)(yr1 + xc1) << 8);
        __half2 W00 = __half2half2(__float2half(wy0 * wx0));
        __half2 W01 = __half2half2(__float2half(wy0 * wx1));
        __half2 W10 = __half2half2(__float2half(wy1 * wx0));
        __half2 W11 = __half2half2(__float2half(wy1 * wx1));

        // ---- per 32-channel slice: gather -> blend -> 8 MFMA ----
#pragma unroll
        for (int s = 0; s < 4; ++s) {
            u32x4 u00 = *(const u32x4*)(fb + (a00 + 64u * s));
            u32x4 u01 = *(const u32x4*)(fb + (a01 + 64u * s));
            u32x4 u10 = *(const u32x4*)(fb + (a10 + 64u * s));
            u32x4 u11 = *(const u32x4*)(fb + (a11 + 64u * s));
            u32x4 bfu;
#pragma unroll
            for (int jd = 0; jd < 4; ++jd) {
                unsigned c00 = u00[jd], c01 = u01[jd], c10 = u10[jd], c11 = u11[jd];
                __half2 r = __hmul2(W00, *(__half2*)&c00);
                r = __hfma2(W01, *(__half2*)&c01, r);
                r = __hfma2(W10, *(__half2*)&c10, r);
                r = __hfma2(W11, *(__half2*)&c11, r);
                bfu[jd] = *(unsigned*)&r;
            }
            f16x8 bf = *(f16x8*)&bfu;
#pragma unroll
            for (int m = 0; m < 8; ++m) {
                f16x8 am = *(const f16x8*)(wc + m * 4096 + aoff[s]);
                acc[m] = __builtin_amdgcn_mfma_f32_16x16x32_f16(am, bf, acc[m], 0, 0, 0);
            }
        }

        // ---- write staged weights to the other LDS buffer, then swap ----
        if (more) {
            _Float16* dst = &wlds[(kp + 1) & 1][stg];
#pragma unroll
            for (int j = 0; j < 8; ++j)
                *(f16x8*)(dst + j * 512) = stgv[j];
        }
        __syncthreads();
    }

    // ---- epilogue: C/D col=lane&15 (position), row = 4*kg + r within each 16-row tile ----
    float* ob = out + ((size_t)b * COUT + 4 * kg) * HW + ho * IW + wox;
#pragma unroll
    for (int m = 0; m < 8; ++m)
#pragma unroll
        for (int r = 0; r < 4; ++r)
            ob[(size_t)(m * 16 + r) * HW] = acc[m][r];
}

extern "C" void kernel_launch(void* const* d_in, const int* in_sizes, int n_in,
                              void* d_out, int out_size, void* d_ws, size_t ws_size,
                              hipStream_t stream) {
    const float* features = (const float*)d_in[0];
    const float* offsets  = (const float*)d_in[1];
    const float* weight   = (const float*)d_in[2];
    float* out = (float*)d_out;

    unsigned*  nhwc = (unsigned*)d_ws;                                     // 31,457,280 B
    _Float16*  wbuf = (_Float16*)((char*)d_ws + (size_t)NB * HW * CIN * 2);

    hipLaunchKernelGGL(k_pre, dim3(4416), dim3(256), 0, stream,
                       features, weight, nhwc, wbuf);
    hipLaunchKernelGGL(k_main, dim3((NB * HW) / 64), dim3(256), 0, stream,
                       offsets, (const char*)nhwc, wbuf, out);
}

// Round 6
// 269.266 us; speedup vs baseline: 1.1799x; 1.0169x over previous
//
#include <hip/hip_runtime.h>
#include <hip/hip_fp16.h>

#define IH   96
#define IW   320
#define NB   4
#define CIN  128
#define COUT 128
#define NKP  9
#define HW   (IH*IW)

typedef float    f32x4 __attribute__((ext_vector_type(4)));
typedef _Float16 f16x8 __attribute__((ext_vector_type(8)));
typedef unsigned u32x4 __attribute__((ext_vector_type(4)));

// ================= pre-pass: transpose + swizzled weight prepack =================
// blocks [0,3840): NCHW f32 -> NHWC f16    [3840,4416): weight -> [kp][row][c^((row&7)<<3)]
__global__ __launch_bounds__(256) void k_pre(const float* __restrict__ feat,
                                             const float* __restrict__ w,
                                             unsigned* __restrict__ nhwc,
                                             _Float16* __restrict__ wb) {
    __shared__ float tile[32][129];
    int bid = blockIdx.x;
    int tid = threadIdx.x;

    if (bid < 3840) {                     // ---- transpose: b*IH*10 + y*10 + xc ----
        int xc = bid % 10;
        int by = bid / 10;
        int y = by % IH;
        int b = by / IH;
        int x0 = xc * 32;
        const float* src = feat + (size_t)b * CIN * HW + (size_t)y * IW + x0;
#pragma unroll
        for (int i = 0; i < 16; ++i) {
            int idx = tid + 256 * i;
            int c = idx >> 5, xl = idx & 31;
            tile[xl][c] = src[(size_t)c * HW + xl];
        }
        __syncthreads();
        unsigned* d = nhwc + ((size_t)(b * IH + y) * IW + x0) * 64;
#pragma unroll
        for (int i = 0; i < 8; ++i) {
            int idx = tid + 256 * i;
            int c2 = idx & 63, xl = idx >> 6;
            __half2 p;
            p.x = __float2half(tile[xl][2 * c2]);
            p.y = __float2half(tile[xl][2 * c2 + 1]);
            d[xl * 64 + c2] = *(unsigned*)&p;
        }
        return;
    }
    bid -= 3840;                          // ---- weight prepack (pre-swizzled source) ----
    int d = bid * 256 + tid;              // dest: kp*16384 + row*128 + j
    int kp = d >> 14;
    int row = (d >> 7) & 127;
    int j = d & 127;
    int csrc = j ^ ((row & 7) << 3);      // involution: LDS read applies the same XOR
    wb[d] = (_Float16)w[(row * CIN + csrc) * NKP + kp];
}

// ================= main kernel =================
// Wave tile: 16 positions x 128 Cout. B-fragments built in registers from dwordx4
// gathers (lane (p=lane&15, kg=lane>>4) gathers channels 8kg..8kg+7 of each slice).
// Weights single-buffered in 32KB LDS, staged via global_load_lds (width 16) from
// the pre-swizzled wbuf; 2 barriers per tap; offsets prefetched one tap ahead.
__global__ __launch_bounds__(256, 4) void k_main(const float* __restrict__ off,
                                                 const char* __restrict__ fb,
                                                 const _Float16* __restrict__ wbuf,
                                                 float* __restrict__ out) {
    __shared__ _Float16 wlds[16384];      // 32 KB, one tap

    const int tid  = threadIdx.x;
    const int lane = tid & 63;
    const int wv   = tid >> 6;
    const int posl = lane & 15;
    const int kg   = lane >> 4;

    const int bid = (blockIdx.x & 7) * 240 + (blockIdx.x >> 3);  // XCD swizzle, 1920=8*240
    const int n0  = bid * 64;
    const int b   = n0 / HW;
    const int rem = n0 - b * HW;
    const int ho  = rem / IW;
    const int wox = rem - ho * IW + wv * 16 + posl;   // this lane's output x

    const float* offp = off + (size_t)b * 18 * HW + ho * IW + wox;
    const unsigned bkg = ((unsigned)(b * HW) << 8) + 16 * kg;   // batch base + k-group byte off

    // A-frag LDS byte offsets per cslice s (within the 32KB tap buffer)
    const int xorv = (posl & 7) << 4;
    int aoff[4];
#pragma unroll
    for (int s = 0; s < 4; ++s)
        aoff[s] = posl * 256 + ((64 * s + 16 * kg) ^ xorv);

    // staging addresses: lane writes 16B at ldsbase + lane*16 (HW-implicit)
    const char* gstage0 = (const char*)wbuf + (size_t)wv * 8192 + lane * 16;

    f32x4 acc[8];
#pragma unroll
    for (int m = 0; m < 8; ++m) acc[m] = (f32x4){0.f, 0.f, 0.f, 0.f};

    // ---- prologue: stage tap 0, prefetch tap-0 offsets ----
#pragma unroll
    for (int j = 0; j < 8; ++j) {
        __builtin_amdgcn_global_load_lds(
            (const __attribute__((address_space(1))) unsigned*)(gstage0 + j * 1024),
            (__attribute__((address_space(3))) unsigned*)((char*)wlds + wv * 8192 + j * 1024),
            16, 0, 0);
    }
    float dy_c = offp[0];
    float dx_c = offp[HW];
    __syncthreads();   // staging + offset loads complete

    for (int kp = 0; kp < NKP; ++kp) {
        const bool more = (kp + 1 < NKP);

        // ---- prefetch next tap's offsets ----
        float dy_n = 0.f, dx_n = 0.f;
        if (more) {
            dy_n = offp[(size_t)(2 * kp + 2) * HW];
            dx_n = offp[(size_t)(2 * kp + 3) * HW];
        }

        // ---- meta (per-lane, its own position) ----
        const int ky = kp / 3, kx = kp - 3 * (kp / 3);
        float py = (float)(ho - 1 + ky) + dy_c;
        float px = (float)(wox - 1 + kx) + dx_c;
        float y0f = floorf(py), x0f = floorf(px);
        float wy1 = py - y0f, wx1 = px - x0f;
        float wy0 = 1.f - wy1, wx0 = 1.f - wx1;
        int y0 = (int)y0f, x0 = (int)x0f, y1 = y0 + 1, x1 = x0 + 1;
        wy0 = (y0 >= 0 && y0 < IH) ? wy0 : 0.f;
        wy1 = (y1 >= 0 && y1 < IH) ? wy1 : 0.f;
        wx0 = (x0 >= 0 && x0 < IW) ? wx0 : 0.f;
        wx1 = (x1 >= 0 && x1 < IW) ? wx1 : 0.f;
        int yr0 = min(max(y0, 0), IH - 1) * IW, yr1 = min(max(y1, 0), IH - 1) * IW;
        int xc0 = min(max(x0, 0), IW - 1), xc1 = min(max(x1, 0), IW - 1);
        unsigned a00 = bkg + ((unsigned)(yr0 + xc0) << 8);
        unsigned a01 = bkg + ((unsigned)(yr0 + xc1) << 8);
        unsigned a10 = bkg + ((unsigned)(yr1 + xc0) << 8);
        unsigned a11 = bkg + ((unsigned)(yr1 + xc1) << 8);
        __half2 W00 = __half2half2(__float2half(wy0 * wx0));
        __half2 W01 = __half2half2(__float2half(wy0 * wx1));
        __half2 W10 = __half2half2(__float2half(wy1 * wx0));
        __half2 W11 = __half2half2(__float2half(wy1 * wx1));

        // ---- issue ALL 16 gathers for this tap ----
        u32x4 g00[4], g01[4], g10[4], g11[4];
#pragma unroll
        for (int s = 0; s < 4; ++s) {
            g00[s] = *(const u32x4*)(fb + (a00 + 64u * s));
            g01[s] = *(const u32x4*)(fb + (a01 + 64u * s));
            g10[s] = *(const u32x4*)(fb + (a10 + 64u * s));
            g11[s] = *(const u32x4*)(fb + (a11 + 64u * s));
        }

        // ---- per 32-channel slice: blend -> 8 MFMA ----
#pragma unroll
        for (int s = 0; s < 4; ++s) {
            u32x4 bfu;
#pragma unroll
            for (int jd = 0; jd < 4; ++jd) {
                unsigned c00 = g00[s][jd], c01 = g01[s][jd], c10 = g10[s][jd], c11 = g11[s][jd];
                __half2 r = __hmul2(W00, *(__half2*)&c00);
                r = __hfma2(W01, *(__half2*)&c01, r);
                r = __hfma2(W10, *(__half2*)&c10, r);
                r = __hfma2(W11, *(__half2*)&c11, r);
                bfu[jd] = *(unsigned*)&r;
            }
            f16x8 bf = *(f16x8*)&bfu;
#pragma unroll
            for (int m = 0; m < 8; ++m) {
                f16x8 am = *(const f16x8*)((const char*)wlds + m * 4096 + aoff[s]);
                acc[m] = __builtin_amdgcn_mfma_f32_16x16x32_f16(am, bf, acc[m], 0, 0, 0);
            }
        }

        dy_c = dy_n;
        dx_c = dx_n;

        // ---- restage LDS with next tap's weights ----
        if (more) {
            __syncthreads();   // all waves done reading tap kp
            const char* gs = gstage0 + (size_t)(kp + 1) * 32768;
#pragma unroll
            for (int j = 0; j < 8; ++j) {
                __builtin_amdgcn_global_load_lds(
                    (const __attribute__((address_space(1))) unsigned*)(gs + j * 1024),
                    (__attribute__((address_space(3))) unsigned*)((char*)wlds + wv * 8192 + j * 1024),
                    16, 0, 0);
            }
            __syncthreads();   // staging landed (vmcnt drained by barrier)
        }
    }

    // ---- epilogue: C/D col=posl (position), row = 4*kg + r within each 16-row tile ----
    float* ob = out + ((size_t)b * COUT + 4 * kg) * HW + ho * IW + wox;
#pragma unroll
    for (int m = 0; m < 8; ++m)
#pragma unroll
        for (int r = 0; r < 4; ++r)
            ob[(size_t)(m * 16 + r) * HW] = acc[m][r];
}

extern "C" void kernel_launch(void* const* d_in, const int* in_sizes, int n_in,
                              void* d_out, int out_size, void* d_ws, size_t ws_size,
                              hipStream_t stream) {
    const float* features = (const float*)d_in[0];
    const float* offsets  = (const float*)d_in[1];
    const float* weight   = (const float*)d_in[2];
    float* out = (float*)d_out;

    unsigned*  nhwc = (unsigned*)d_ws;                                     // 31,457,280 B
    _Float16*  wbuf = (_Float16*)((char*)d_ws + (size_t)NB * HW * CIN * 2);

    hipLaunchKernelGGL(k_pre, dim3(4416), dim3(256), 0, stream,
                       features, weight, nhwc, wbuf);
    hipLaunchKernelGGL(k_main, dim3((NB * HW) / 64), dim3(256), 0, stream,
                       offsets, (const char*)nhwc, wbuf, out);
}